// Round 11
// baseline (50.933 us; speedup 1.0000x reference)
//
#include <hip/hip_runtime.h>
#include <math.h>

#define BB 256
#define NN 196
#define DD 768
#define TDK 32
#define NHALF 2
#define DHALF (DD / NHALF)  // 384
#define NTILES (DHALF / TDK) // 12
#define SROW 224            // tile row stride in floats: 896 B = 0 mod 32 banks
#define NITEMS (NN * 8)     // 1568 items per tile (load side; also 32*49 store side)
#define NW 8                // waves per block (512 threads)

typedef float f32x4 __attribute__((ext_vector_type(4)));

// LDS-only barrier: orders LDS ops across the block WITHOUT draining vmcnt.
__device__ __forceinline__ void lds_barrier() {
    asm volatile("s_waitcnt lgkmcnt(0)" ::: "memory");
    __builtin_amdgcn_s_barrier();
    asm volatile("" ::: "memory");
}

// grid (BB, 2), 512 threads: block (b,h) does phase A redundantly (second read
// is L3-absorbed — R7 FETCH evidence), then phase B on d-range [h*384,(h+1)*384).
// Two INDEPENDENT barrier domains per CU -> store issue stays continuous.
__global__ __launch_bounds__(512) void fused_kernel(
    const float* __restrict__ features,  // [B,N,D]
    const float* __restrict__ logits,    // [B,N,N]
    float* __restrict__ img,             // [B,D,N]
    float* __restrict__ conf_out)        // [B,N]
{
    const int b = blockIdx.x;
    const int h = blockIdx.y;
    const int t = threadIdx.x;

    __shared__ union {
        struct { float sm[NW][NN]; float ss[NW][NN]; int si[NW][NN]; } a;  // 18816 B
        float tiles[2][TDK * SROW];                                        // 57344 B
    } u;
    __shared__ int winner_s[NN];

    // ---------------- Phase A: pos + conf ----------------
    const int wv = t >> 6;               // 0..7: row chunk
    const int l  = t & 63;

    if (t < NN) winner_s[t] = -1;

    {
        const int i0 = (49 * wv) >> 1;           // 8 chunks covering rows 0..195
        const int i1 = (49 * (wv + 1)) >> 1;
        if (l < 49) {
            const float* basep = logits + (size_t)b * NN * NN + 4 * l;
            f32x4 m = {-INFINITY, -INFINITY, -INFINITY, -INFINITY};
            f32x4 s = {0.f, 0.f, 0.f, 0.f};
            int4 idx = make_int4(0, 0, 0, 0);
            #pragma unroll 4
            for (int i = i0; i < i1; ++i) {
                const f32x4 x = *reinterpret_cast<const f32x4*>(basep + (size_t)i * NN);
                f32x4 mn;
                mn.x = fmaxf(m.x, x.x); mn.y = fmaxf(m.y, x.y);
                mn.z = fmaxf(m.z, x.z); mn.w = fmaxf(m.w, x.w);
                idx.x = (x.x > m.x) ? i : idx.x;   // strict >: first occurrence
                idx.y = (x.y > m.y) ? i : idx.y;
                idx.z = (x.z > m.z) ? i : idx.z;
                idx.w = (x.w > m.w) ? i : idx.w;
                s.x = s.x * __expf(m.x - mn.x) + __expf(x.x - mn.x);
                s.y = s.y * __expf(m.y - mn.y) + __expf(x.y - mn.y);
                s.z = s.z * __expf(m.z - mn.z) + __expf(x.z - mn.z);
                s.w = s.w * __expf(m.w - mn.w) + __expf(x.w - mn.w);
                m = mn;
            }
            const int c = 4 * l;
            u.a.sm[wv][c + 0] = m.x; u.a.ss[wv][c + 0] = s.x; u.a.si[wv][c + 0] = idx.x;
            u.a.sm[wv][c + 1] = m.y; u.a.ss[wv][c + 1] = s.y; u.a.si[wv][c + 1] = idx.y;
            u.a.sm[wv][c + 2] = m.z; u.a.ss[wv][c + 2] = s.z; u.a.si[wv][c + 2] = idx.z;
            u.a.sm[wv][c + 3] = m.w; u.a.ss[wv][c + 3] = s.w; u.a.si[wv][c + 3] = idx.w;
        }
    }
    __syncthreads();

    if (t < NN) {
        const int j = t;
        float m = -INFINITY;
        int idx = 0;
        #pragma unroll
        for (int ww = 0; ww < NW; ++ww) {    // ascending rows: earliest chunk wins ties
            const float mg = u.a.sm[ww][j];
            if (mg > m) { m = mg; idx = u.a.si[ww][j]; }
        }
        float s = 0.0f;
        #pragma unroll
        for (int ww = 0; ww < NW; ++ww)
            s += u.a.ss[ww][j] * __expf(u.a.sm[ww][j] - m);
        if (h == 0) conf_out[b * NN + j] = 1.0f / s;
        atomicMax(&winner_s[idx], j);        // winner[p] = max j with pos[j]==p
    }
    __syncthreads();                         // winner ready; phase-A arrays dead

    // ---------------- Phase B: gather + smooth + transpose-store ----------------
    const float* fb = features + (size_t)b * NN * DD;
    const int D0 = h * DHALF;
    float* ob = img + (size_t)b * DD * NN + (size_t)D0 * NN;

    // Load-side items: item = r*8 + k; 1568 items / 512 threads -> 4 slots.
    int  rr[4], k4[4], wn[4], col[4];
    bool act[4];
    #pragma unroll
    for (int i = 0; i < 4; ++i) {
        const int item = t + 512 * i;
        act[i] = (item < NITEMS);
        rr[i]  = act[i] ? (item >> 3) : 0;
        k4[i]  = (item & 7) * 4;
        wn[i]  = act[i] ? winner_s[rr[i]] : -1;
        // swizzle: element (d,p) at d*SROW + ((p>>2)^((d>>2)&7))*4 + (p&3)
        col[i] = (((rr[i] >> 2) ^ (k4[i] >> 2)) << 2) + (rr[i] & 3);
    }

    const f32x4 zero = {0.f, 0.f, 0.f, 0.f};
    f32x4 cur[4], nxt[4];
    #pragma unroll
    for (int i = 0; i < 4; ++i)
        cur[i] = (wn[i] >= 0)
            ? *reinterpret_cast<const f32x4*>(fb + (size_t)wn[i] * DD + D0 + k4[i])
            : zero;

    for (int kt = 0; kt < NTILES; ++kt) {
        float* buf = u.tiles[kt & 1];

        // Swizzled transpose-write of current tile (counted vmcnt wait only).
        #pragma unroll
        for (int i = 0; i < 4; ++i) {
            if (act[i]) {
                buf[(k4[i] + 0) * SROW + col[i]] = cur[i].x;
                buf[(k4[i] + 1) * SROW + col[i]] = cur[i].y;
                buf[(k4[i] + 2) * SROW + col[i]] = cur[i].z;
                buf[(k4[i] + 3) * SROW + col[i]] = cur[i].w;
            }
        }

        // Issue next tile's gathers; stay in flight across the lgkm-only barrier.
        #pragma unroll
        for (int i = 0; i < 4; ++i) nxt[i] = zero;
        if (kt + 1 < NTILES) {
            const int dn = D0 + (kt + 1) * TDK;
            #pragma unroll
            for (int i = 0; i < 4; ++i)
                if (wn[i] >= 0)
                    nxt[i] = *reinterpret_cast<const f32x4*>(fb + (size_t)wn[i] * DD + dn + k4[i]);
        }

        lds_barrier();                       // LDS-ordering only; vmcnt untouched

        // Smooth + contiguous nontemporal stores: q -> (dl = q/49, c = q%49).
        const int dg0 = kt * TDK;
        #pragma unroll
        for (int it = 0; it < 4; ++it) {
            const int q = t + 512 * it;
            if (q < NITEMS) {
                const int dl  = q / 49;
                const int c   = q - 49 * dl;
                const int key = (dl >> 2) & 7;
                const float* row = &buf[dl * SROW];
                const f32x4 ctr = *reinterpret_cast<const f32x4*>(row + ((c ^ key) << 2));
                const float left  = (c > 0)  ? row[(((c - 1) ^ key) << 2) + 3] : 0.0f;
                const float right = (c < 48) ? row[ ((c + 1) ^ key) << 2      ] : 0.0f;
                const int p0 = 4 * c;
                f32x4 o;
                o.x = (p0 == 0)          ? ctr.x : (left  + ctr.x + ctr.y) * (1.0f / 3.0f);
                o.y = (ctr.x + ctr.y + ctr.z) * (1.0f / 3.0f);
                o.z = (ctr.y + ctr.z + ctr.w) * (1.0f / 3.0f);
                o.w = (p0 + 3 == NN - 1) ? ctr.w : (ctr.z + ctr.w + right) * (1.0f / 3.0f);
                __builtin_nontemporal_store(o, reinterpret_cast<f32x4*>(ob + (size_t)(dg0 + dl) * NN + p0));
            }
        }
        #pragma unroll
        for (int i = 0; i < 4; ++i) cur[i] = nxt[i];
        // No trailing barrier: next iteration writes the OTHER buffer; the
        // k -> k+2 reuse hazard is ordered by the next lds_barrier.
    }
}

extern "C" void kernel_launch(void* const* d_in, const int* in_sizes, int n_in,
                              void* d_out, int out_size, void* d_ws, size_t ws_size,
                              hipStream_t stream) {
    const float* features = (const float*)d_in[0];
    const float* logits   = (const float*)d_in[1];

    float* out  = (float*)d_out;
    float* img  = out;                              // B*D*N floats
    float* conf = out + (size_t)BB * DD * NN;       // B*N floats

    dim3 grid(BB, NHALF);
    fused_kernel<<<grid, 512, 0, stream>>>(features, logits, img, conf);
}